// Round 8
// baseline (440.687 us; speedup 1.0000x reference)
//
#include <hip/hip_runtime.h>
#include <hip/hip_bf16.h>

#define NN 50000
#define EE 600000
#define HH 128
#define OUTD 32
#define RR 64
#define BB 16
#define KK 2048   // BB*HH
#define SC_B ((NN + 1023) / 1024)  // 49 scan chunks

typedef short s16x8 __attribute__((ext_vector_type(8)));
typedef float f32x4 __attribute__((ext_vector_type(4)));
typedef unsigned short ushort_t;
typedef unsigned int uint_t;

__device__ inline ushort_t f_to_bf16(float f){
    __hip_bfloat16 h = __float2bfloat16(f);
    return *reinterpret_cast<ushort_t*>(&h);
}
__device__ inline uint_t pack_bf16x2(float a, float b){
    return (uint_t)f_to_bf16(a) | ((uint_t)f_to_bf16(b) << 16);
}
__device__ inline float bf16_lo(uint_t u){ return __uint_as_float(u << 16); }
__device__ inline float bf16_hi(uint_t u){ return __uint_as_float(u & 0xffff0000u); }

__global__ void zero_i32(int* p, int n){
    int i = blockIdx.x*256 + threadIdx.x;
    if (i < n) p[i] = 0;
}

__global__ void hist_kernel(const int* __restrict__ dst, int* counts){
    int e = blockIdx.x*256 + threadIdx.x;
    if (e < EE) atomicAdd(&counts[dst[e]], 1);
}

// ---- hierarchical scan: chunk totals -> scan totals -> final ----
__global__ void scan_part(const int* __restrict__ counts, int* __restrict__ tot){
    int b = blockIdx.x, t = threadIdx.x;
    int i0 = b*1024 + t*4;
    int s = 0;
    if (i0 + 3 < NN){
        int4 v = *reinterpret_cast<const int4*>(&counts[i0]);
        s = v.x + v.y + v.z + v.w;
    } else {
        for (int j = 0; j < 4; j++) if (i0 + j < NN) s += counts[i0 + j];
    }
    #pragma unroll
    for (int off = 32; off; off >>= 1) s += __shfl_xor(s, off, 64);
    __shared__ int ws[4];
    if ((t & 63) == 0) ws[t >> 6] = s;
    __syncthreads();
    if (t == 0) tot[b] = ws[0] + ws[1] + ws[2] + ws[3];
}

__global__ void scan_tot(int* tot){  // 1 block, 64 threads (SC_B <= 64)
    int t = threadIdx.x;
    int v = (t < SC_B) ? tot[t] : 0;
    int x = v;
    #pragma unroll
    for (int off = 1; off < 64; off <<= 1){
        int y = __shfl_up(x, off, 64);
        if (t >= off) x += y;
    }
    if (t < SC_B) tot[t] = x - v;  // exclusive base per chunk
}

__global__ void scan_final(const int* __restrict__ counts, const int* __restrict__ tot,
                           int* __restrict__ offsets, int* __restrict__ cursor){
    int b = blockIdx.x, t = threadIdx.x, lane = t & 63, wv = t >> 6;
    int i0 = b*1024 + t*4;
    int v[4]; int s = 0;
    #pragma unroll
    for (int j = 0; j < 4; j++){ v[j] = (i0 + j < NN) ? counts[i0 + j] : 0; s += v[j]; }
    int x = s;
    #pragma unroll
    for (int off = 1; off < 64; off <<= 1){
        int y = __shfl_up(x, off, 64);
        if (lane >= off) x += y;
    }
    __shared__ int ws[4];
    if (lane == 63) ws[wv] = x;
    __syncthreads();
    int pre = tot[b];
    for (int i = 0; i < wv; i++) pre += ws[i];
    int run = pre + x - s;  // exclusive start of this thread's 4 elems
    #pragma unroll
    for (int j = 0; j < 4; j++){
        if (i0 + j < NN){
            cursor[i0 + j] = run;
            offsets[i0 + j + 1] = run + v[j];
        }
        run += v[j];
    }
    if (b == 0 && t == 0) offsets[0] = 0;
}

// scatter dst-sorted edge payload: msrcet[r] = (src<<6)|etype, normA[r] = norm
__global__ void scatter_kernel(const int* __restrict__ dst, const int* __restrict__ src,
                               const int* __restrict__ etype, const float* __restrict__ norm,
                               int* cursor, uint_t* __restrict__ msrcet,
                               float* __restrict__ normA){
    int e = blockIdx.x*256 + threadIdx.x;
    if (e >= EE) return;
    int d = dst[e];
    int r = atomicAdd(&cursor[d], 1);
    msrcet[r] = ((uint_t)src[e] << 6) | (uint_t)etype[e];
    normA[r] = norm[e];
}

// transposed bf16 weights: Wt1[o][k] = V1[k][o] (k = b*H+i), Wt2[o][k] = V2[k][o]
__global__ void convw_kernel(const float* __restrict__ V1, const float* __restrict__ V2,
                             ushort_t* __restrict__ Wt1, ushort_t* __restrict__ Wt2){
    int i = blockIdx.x*256 + threadIdx.x;
    if (i < HH*KK){
        int o = i / KK, k = i % KK;
        Wt1[i] = f_to_bf16(V1[(size_t)k*HH + o]);
    } else {
        int j = i - HH*KK;
        if (j < OUTD*KK){
            int o = j / KK, k = j % KK;
            Wt2[j] = f_to_bf16(V2[(size_t)k*OUTD + o]);
        }
    }
}

__global__ void conv_emb(const float* __restrict__ emb, ushort_t* __restrict__ xb){
    int i = blockIdx.x*256 + threadIdx.x;
    if (i < NN*HH/2){
        float2 f = *reinterpret_cast<const float2*>(emb + 2*(size_t)i);
        *reinterpret_cast<uint_t*>(xb + 2*(size_t)i) = pack_bf16x2(f.x, f.y);
    }
}

// Aggregate: 1 node per wave, 4 waves/block, no LDS/barriers. Per <=64-edge
// chunk: metas into lane registers (2 coalesced loads), then an 8-deep
// register ring of independent coalesced 256B x-row loads; consume = 32
// SGPR-operand FMAs per edge (comp via scalar cache). agg row stored bf16.
__global__ __launch_bounds__(256, 8) void agg_kernel(
    const ushort_t* __restrict__ xin, const uint_t* __restrict__ msrcet,
    const int* __restrict__ normAi, const int* __restrict__ offsets,
    const float* __restrict__ comp, ushort_t* __restrict__ agg,
    int v0, int vc)
{
    int w = threadIdx.x >> 6, lane = threadIdx.x & 63;
    int v = v0 + blockIdx.x*4 + w;
    if (v >= v0 + vc) return;
    int p0 = offsets[v];
    int dd = offsets[v+1] - p0;
    const uint_t* xrow = reinterpret_cast<const uint_t*>(xin);  // row r at xrow + r*64

    float a0[BB], a1[BB];
    #pragma unroll
    for (int b = 0; b < BB; b++){ a0[b] = 0.f; a1[b] = 0.f; }

    for (int c0 = 0; c0 < dd; c0 += 64){
        int nc = min(64, dd - c0);
        int li = p0 + c0 + min(lane, nc - 1);
        uint_t mp = msrcet[li];      // lane e: (src<<6)|etype of edge e
        int    nr = normAi[li];      // lane e: norm bits of edge e
        uint_t xr[8];
        #pragma unroll
        for (int j = 0; j < 8; ++j){
            int sr = (int)(__builtin_amdgcn_readlane(mp, min(j, nc - 1)) >> 6);
            xr[j] = xrow[(size_t)sr*64 + lane];
        }
        for (int eb = 0; eb < nc; eb += 8){
            #pragma unroll
            for (int j = 0; j < 8; ++j){
                int e = eb + j;                       // uniform
                int ec = min(e, nc - 1);
                uint_t me = __builtin_amdgcn_readlane(mp, ec);
                int    nb = __builtin_amdgcn_readlane(nr, ec);
                float  nw = (e < nc) ? __int_as_float(nb) : 0.f;
                uint_t u = xr[j];
                float xa = bf16_lo(u)*nw, xb = bf16_hi(u)*nw;
                int en = e + 8;
                if (en < nc){                          // uniform branch: refill ring
                    int srn = (int)(__builtin_amdgcn_readlane(mp, en) >> 6);
                    xr[j] = xrow[(size_t)srn*64 + lane];
                }
                const float* c = comp + (me & 63)*BB;  // uniform -> scalar loads
                #pragma unroll
                for (int b = 0; b < BB; b++){
                    a0[b] = fmaf(c[b], xa, a0[b]);
                    a1[b] = fmaf(c[b], xb, a1[b]);
                }
            }
        }
    }
    // store chunk-local agg row (bf16x2 packed, coalesced 256B per basis)
    uint_t* arow = reinterpret_cast<uint_t*>(agg) + (size_t)(v - v0)*1024 + lane;
    #pragma unroll
    for (int b = 0; b < BB; b++) arow[b*64] = pack_bf16x2(a0[b], a1[b]);
}

// GEMM: C[m, o] = sum_k A[m,k] * Wt[o,k] (+bias, opt relu). 128xBN tile,
// 256 thr (4 waves), wave w owns rows [w*32, w*32+32) as 2 MFMA row-tiles.
template<int BN, bool RELU, bool OUT_BF16>
__global__ __launch_bounds__(256, 4) void gemm_kernel(
    const ushort_t* __restrict__ A, const ushort_t* __restrict__ Wt,
    const float* __restrict__ bias, void* __restrict__ yout, int vc)
{
    __shared__ ushort_t Alds[128][72];
    __shared__ ushort_t Blds[BN][72];
    int tid = threadIdx.x, w = tid >> 6, lane = tid & 63, lane15 = lane & 15;
    int m0 = blockIdx.x * 128;
    int kc8 = (lane >> 4) * 8;

    f32x4 acc[2][BN/16];
    #pragma unroll
    for (int t = 0; t < 2; t++)
        #pragma unroll
        for (int nt = 0; nt < BN/16; nt++)
            #pragma unroll
            for (int j = 0; j < 4; j++) acc[t][nt][j] = 0.f;

    for (int k0 = 0; k0 < KK; k0 += 64){
        #pragma unroll
        for (int i = 0; i < 4; i++){
            int idx = tid + i*256;
            int row = idx >> 3, kc = (idx & 7)*8;
            uint4 val = make_uint4(0u,0u,0u,0u);
            if (m0 + row < vc)
                val = *reinterpret_cast<const uint4*>(A + (size_t)(m0+row)*KK + k0 + kc);
            *reinterpret_cast<uint4*>(&Alds[row][kc]) = val;
        }
        #pragma unroll
        for (int i = 0; i < BN/32; i++){
            int idx = tid + i*256;
            int row = idx >> 3, kc = (idx & 7)*8;
            *reinterpret_cast<uint4*>(&Blds[row][kc]) =
                *reinterpret_cast<const uint4*>(Wt + (size_t)row*KK + k0 + kc);
        }
        __syncthreads();
        #pragma unroll
        for (int ks = 0; ks < 2; ks++){
            s16x8 a0 = *reinterpret_cast<const s16x8*>(&Alds[w*32 + lane15][ks*32 + kc8]);
            s16x8 a1 = *reinterpret_cast<const s16x8*>(&Alds[w*32 + 16 + lane15][ks*32 + kc8]);
            #pragma unroll
            for (int nt = 0; nt < BN/16; nt++){
                s16x8 b = *reinterpret_cast<const s16x8*>(&Blds[nt*16 + lane15][ks*32 + kc8]);
                acc[0][nt] = __builtin_amdgcn_mfma_f32_16x16x32_bf16(a0, b, acc[0][nt], 0,0,0);
                acc[1][nt] = __builtin_amdgcn_mfma_f32_16x16x32_bf16(a1, b, acc[1][nt], 0,0,0);
            }
        }
        __syncthreads();
    }
    #pragma unroll
    for (int t = 0; t < 2; t++){
        int rb = m0 + w*32 + t*16 + ((lane >> 4) << 2);
        #pragma unroll
        for (int nt = 0; nt < BN/16; nt++){
            int col = nt*16 + lane15;
            float bv = bias[col];
            #pragma unroll
            for (int r = 0; r < 4; r++){
                int row = rb + r;
                if (row < vc){
                    float val = acc[t][nt][r] + bv;
                    if (RELU) val = fmaxf(val, 0.f);
                    if (OUT_BF16)
                        reinterpret_cast<ushort_t*>(yout)[(size_t)row*BN + col] = f_to_bf16(val);
                    else
                        reinterpret_cast<float*>(yout)[(size_t)row*BN + col] = val;
                }
            }
        }
    }
}

extern "C" void kernel_launch(void* const* d_in, const int* in_sizes, int n_in,
                              void* d_out, int out_size, void* d_ws, size_t ws_size,
                              hipStream_t stream){
    const int*   src   = (const int*)d_in[0];
    const int*   dst   = (const int*)d_in[1];
    const int*   etype = (const int*)d_in[2];
    const float* norm  = (const float*)d_in[3];
    const float* emb   = (const float*)d_in[4];
    const float* V1    = (const float*)d_in[5];
    const float* comp1 = (const float*)d_in[6];
    const float* bias1 = (const float*)d_in[7];
    const float* V2    = (const float*)d_in[8];
    const float* comp2 = (const float*)d_in[9];
    const float* bias2 = (const float*)d_in[10];
    float* out = (float*)d_out;

    char* w = (char*)d_ws;
    auto alloc = [&](size_t bytes) -> char* {
        char* p = w; w += (bytes + 255) & ~(size_t)255; return p;
    };
    int*      offsets = (int*)alloc((NN + 1) * 4);
    int*      counts  = (int*)alloc(NN * 4);
    int*      cursor  = (int*)alloc(NN * 4);
    int*      tot     = (int*)alloc(SC_B * 4);
    uint_t*   msrcet  = (uint_t*)alloc((size_t)EE * 4);
    float*    normA   = (float*)alloc((size_t)EE * 4);
    ushort_t* Wt1     = (ushort_t*)alloc((size_t)HH * KK * 2);
    ushort_t* Wt2     = (ushort_t*)alloc((size_t)OUTD * KK * 2);
    ushort_t* xb      = (ushort_t*)alloc((size_t)NN * HH * 2);
    ushort_t* h       = (ushort_t*)alloc((size_t)NN * HH * 2);
    size_t used  = (size_t)(w - (char*)d_ws);
    size_t avail = ws_size > used ? ws_size - used : 0;
    int chunkN = (int)(avail / ((size_t)KK * 2));
    chunkN &= ~127;
    if (chunkN < 128) chunkN = 128;
    if (chunkN > NN) chunkN = NN;
    ushort_t* agg = (ushort_t*)w;

    // CSR build + payload sort + weight/emb conversion
    zero_i32<<<(NN + 255)/256, 256, 0, stream>>>(counts, NN);
    hist_kernel<<<(EE + 255)/256, 256, 0, stream>>>(dst, counts);
    scan_part<<<SC_B, 256, 0, stream>>>(counts, tot);
    scan_tot<<<1, 64, 0, stream>>>(tot);
    scan_final<<<SC_B, 256, 0, stream>>>(counts, tot, offsets, cursor);
    scatter_kernel<<<(EE + 255)/256, 256, 0, stream>>>(dst, src, etype, norm,
                                                       cursor, msrcet, normA);
    convw_kernel<<<((HH + OUTD)*KK + 255)/256, 256, 0, stream>>>(V1, V2, Wt1, Wt2);
    conv_emb<<<(NN*HH/2 + 255)/256, 256, 0, stream>>>(emb, xb);

    // layer 1: xb (bf16) -> h (bf16, relu)
    for (int v0 = 0; v0 < NN; v0 += chunkN){
        int vc = (NN - v0 < chunkN) ? (NN - v0) : chunkN;
        agg_kernel<<<(vc + 3)/4, 256, 0, stream>>>(
            xb, msrcet, (const int*)normA, offsets, comp1, agg, v0, vc);
        gemm_kernel<HH, true, true><<<(vc + 127)/128, 256, 0, stream>>>(
            agg, Wt1, bias1, h + (size_t)v0 * HH, vc);
    }
    // layer 2: h (bf16) -> out (f32)
    for (int v0 = 0; v0 < NN; v0 += chunkN){
        int vc = (NN - v0 < chunkN) ? (NN - v0) : chunkN;
        agg_kernel<<<(vc + 3)/4, 256, 0, stream>>>(
            h, msrcet, (const int*)normA, offsets, comp2, agg, v0, vc);
        gemm_kernel<OUTD, false, false><<<(vc + 127)/128, 256, 0, stream>>>(
            agg, Wt2, bias2, out + (size_t)v0 * OUTD, vc);
    }
}

// Round 9
// 382.170 us; speedup vs baseline: 1.1531x; 1.1531x over previous
//
#include <hip/hip_runtime.h>
#include <hip/hip_bf16.h>

#define NN 50000
#define EE 600000
#define HH 128
#define OUTD 32
#define RR 64
#define BB 16
#define KK 2048   // BB*HH
#define SC_B ((NN + 1023) / 1024)  // 49 scan chunks

typedef short s16x8 __attribute__((ext_vector_type(8)));
typedef float f32x4 __attribute__((ext_vector_type(4)));
typedef unsigned short ushort_t;
typedef unsigned int uint_t;

__device__ inline ushort_t f_to_bf16(float f){
    __hip_bfloat16 h = __float2bfloat16(f);
    return *reinterpret_cast<ushort_t*>(&h);
}
__device__ inline uint_t pack_bf16x2(float a, float b){
    return (uint_t)f_to_bf16(a) | ((uint_t)f_to_bf16(b) << 16);
}
__device__ inline float bf16_lo(uint_t u){ return __uint_as_float(u << 16); }
__device__ inline float bf16_hi(uint_t u){ return __uint_as_float(u & 0xffff0000u); }

__global__ void zero_i32(int* p, int n){
    int i = blockIdx.x*256 + threadIdx.x;
    if (i < n) p[i] = 0;
}

__global__ void hist_kernel(const int* __restrict__ dst, int* counts){
    int e = blockIdx.x*256 + threadIdx.x;
    if (e < EE) atomicAdd(&counts[dst[e]], 1);
}

// ---- hierarchical scan: chunk totals -> scan totals -> final ----
__global__ void scan_part(const int* __restrict__ counts, int* __restrict__ tot){
    int b = blockIdx.x, t = threadIdx.x;
    int i0 = b*1024 + t*4;
    int s = 0;
    if (i0 + 3 < NN){
        int4 v = *reinterpret_cast<const int4*>(&counts[i0]);
        s = v.x + v.y + v.z + v.w;
    } else {
        for (int j = 0; j < 4; j++) if (i0 + j < NN) s += counts[i0 + j];
    }
    #pragma unroll
    for (int off = 32; off; off >>= 1) s += __shfl_xor(s, off, 64);
    __shared__ int ws[4];
    if ((t & 63) == 0) ws[t >> 6] = s;
    __syncthreads();
    if (t == 0) tot[b] = ws[0] + ws[1] + ws[2] + ws[3];
}

__global__ void scan_tot(int* tot){  // 1 block, 64 threads (SC_B <= 64)
    int t = threadIdx.x;
    int v = (t < SC_B) ? tot[t] : 0;
    int x = v;
    #pragma unroll
    for (int off = 1; off < 64; off <<= 1){
        int y = __shfl_up(x, off, 64);
        if (t >= off) x += y;
    }
    if (t < SC_B) tot[t] = x - v;  // exclusive base per chunk
}

__global__ void scan_final(const int* __restrict__ counts, const int* __restrict__ tot,
                           int* __restrict__ offsets, int* __restrict__ cursor){
    int b = blockIdx.x, t = threadIdx.x, lane = t & 63, wv = t >> 6;
    int i0 = b*1024 + t*4;
    int v[4]; int s = 0;
    #pragma unroll
    for (int j = 0; j < 4; j++){ v[j] = (i0 + j < NN) ? counts[i0 + j] : 0; s += v[j]; }
    int x = s;
    #pragma unroll
    for (int off = 1; off < 64; off <<= 1){
        int y = __shfl_up(x, off, 64);
        if (lane >= off) x += y;
    }
    __shared__ int ws[4];
    if (lane == 63) ws[wv] = x;
    __syncthreads();
    int pre = tot[b];
    for (int i = 0; i < wv; i++) pre += ws[i];
    int run = pre + x - s;  // exclusive start of this thread's 4 elems
    #pragma unroll
    for (int j = 0; j < 4; j++){
        if (i0 + j < NN){
            cursor[i0 + j] = run;
            offsets[i0 + j + 1] = run + v[j];
        }
        run += v[j];
    }
    if (b == 0 && t == 0) offsets[0] = 0;
}

// scatter dst-sorted edge payload: msrcet[r] = (src<<6)|etype, normA[r] = norm
__global__ void scatter_kernel(const int* __restrict__ dst, const int* __restrict__ src,
                               const int* __restrict__ etype, const float* __restrict__ norm,
                               int* cursor, uint_t* __restrict__ msrcet,
                               float* __restrict__ normA){
    int e = blockIdx.x*256 + threadIdx.x;
    if (e >= EE) return;
    int d = dst[e];
    int r = atomicAdd(&cursor[d], 1);
    msrcet[r] = ((uint_t)src[e] << 6) | (uint_t)etype[e];
    normA[r] = norm[e];
}

// transposed bf16 weights: Wt1[o][k] = V1[k][o] (k = b*H+i), Wt2[o][k] = V2[k][o]
__global__ void convw_kernel(const float* __restrict__ V1, const float* __restrict__ V2,
                             ushort_t* __restrict__ Wt1, ushort_t* __restrict__ Wt2){
    int i = blockIdx.x*256 + threadIdx.x;
    if (i < HH*KK){
        int o = i / KK, k = i % KK;
        Wt1[i] = f_to_bf16(V1[(size_t)k*HH + o]);
    } else {
        int j = i - HH*KK;
        if (j < OUTD*KK){
            int o = j / KK, k = j % KK;
            Wt2[j] = f_to_bf16(V2[(size_t)k*OUTD + o]);
        }
    }
}

__global__ void conv_emb(const float* __restrict__ emb, ushort_t* __restrict__ xb){
    int i = blockIdx.x*256 + threadIdx.x;
    if (i < NN*HH/2){
        float2 f = *reinterpret_cast<const float2*>(emb + 2*(size_t)i);
        *reinterpret_cast<uint_t*>(xb + 2*(size_t)i) = pack_bf16x2(f.x, f.y);
    }
}

// Aggregate: 1 node per wave, 4 waves/block, no LDS/barriers. Per <=64-edge
// chunk: metas into lane registers (2 coalesced loads), then an 8-deep
// register ring of independent coalesced 256B x-row loads; consume = 32
// SGPR-operand FMAs per edge (comp via scalar cache). agg row stored bf16.
__global__ __launch_bounds__(256, 8) void agg_kernel(
    const ushort_t* __restrict__ xin, const uint_t* __restrict__ msrcet,
    const int* __restrict__ normAi, const int* __restrict__ offsets,
    const float* __restrict__ comp, ushort_t* __restrict__ agg,
    int v0, int vc)
{
    int w = threadIdx.x >> 6, lane = threadIdx.x & 63;
    int v = v0 + blockIdx.x*4 + w;
    if (v >= v0 + vc) return;
    int p0 = offsets[v];
    int dd = offsets[v+1] - p0;
    const uint_t* xrow = reinterpret_cast<const uint_t*>(xin);  // row r at xrow + r*64

    float a0[BB], a1[BB];
    #pragma unroll
    for (int b = 0; b < BB; b++){ a0[b] = 0.f; a1[b] = 0.f; }

    for (int c0 = 0; c0 < dd; c0 += 64){
        int nc = min(64, dd - c0);
        int li = p0 + c0 + min(lane, nc - 1);
        uint_t mp = msrcet[li];      // lane e: (src<<6)|etype of edge e
        int    nr = normAi[li];      // lane e: norm bits of edge e
        uint_t xr[8];
        #pragma unroll
        for (int j = 0; j < 8; ++j){
            int sr = (int)(__builtin_amdgcn_readlane(mp, min(j, nc - 1)) >> 6);
            xr[j] = xrow[(size_t)sr*64 + lane];
        }
        for (int eb = 0; eb < nc; eb += 8){
            #pragma unroll
            for (int j = 0; j < 8; ++j){
                int e = eb + j;                       // uniform
                int ec = min(e, nc - 1);
                uint_t me = __builtin_amdgcn_readlane(mp, ec);
                int    nb = __builtin_amdgcn_readlane(nr, ec);
                float  nw = (e < nc) ? __int_as_float(nb) : 0.f;
                uint_t u = xr[j];
                float xa = bf16_lo(u)*nw, xb = bf16_hi(u)*nw;
                int en = e + 8;
                if (en < nc){                          // uniform branch: refill ring
                    int srn = (int)(__builtin_amdgcn_readlane(mp, en) >> 6);
                    xr[j] = xrow[(size_t)srn*64 + lane];
                }
                const float* c = comp + (me & 63)*BB;  // uniform -> scalar loads
                #pragma unroll
                for (int b = 0; b < BB; b++){
                    a0[b] = fmaf(c[b], xa, a0[b]);
                    a1[b] = fmaf(c[b], xb, a1[b]);
                }
            }
        }
    }
    // store chunk-local agg row (bf16x2 packed, coalesced 256B per basis)
    uint_t* arow = reinterpret_cast<uint_t*>(agg) + (size_t)(v - v0)*1024 + lane;
    #pragma unroll
    for (int b = 0; b < BB; b++) arow[b*64] = pack_bf16x2(a0[b], a1[b]);
}

// GEMM: C[m, o] = sum_k A[m,k] * Wt[o,k] (+bias, opt relu). 64xBN tile,
// 512 thr (8 waves: 4 row-tiles x 2 col-halves). A read exactly once (BN = full
// output width). Grid ~ (vc/64) for occupancy.
template<int BN, bool RELU, bool OUT_BF16>
__global__ __launch_bounds__(512, 6) void gemm_kernel(
    const ushort_t* __restrict__ A, const ushort_t* __restrict__ Wt,
    const float* __restrict__ bias, void* __restrict__ yout, int vc)
{
    __shared__ ushort_t Alds[64][72];
    __shared__ ushort_t Blds[BN][72];
    constexpr int CT = BN / 32;        // col-tiles per wave (BN=128 -> 4, BN=32 -> 1)
    int tid = threadIdx.x, lane = tid & 63, lane15 = lane & 15;
    int w = tid >> 6, wr = w >> 1, wc = w & 1;
    int m0 = blockIdx.x * 64;
    int kc8 = (lane >> 4) * 8;

    f32x4 acc[CT];
    #pragma unroll
    for (int ct = 0; ct < CT; ct++)
        #pragma unroll
        for (int j = 0; j < 4; j++) acc[ct][j] = 0.f;

    for (int k0 = 0; k0 < KK; k0 += 64){
        {   // stage A 64x64: exactly one uint4 per thread
            int row = tid >> 3, kc = (tid & 7) * 8;
            uint4 val = make_uint4(0u,0u,0u,0u);
            if (m0 + row < vc)
                val = *reinterpret_cast<const uint4*>(A + (size_t)(m0+row)*KK + k0 + kc);
            *reinterpret_cast<uint4*>(&Alds[row][kc]) = val;
        }
        if (BN == 128){
            #pragma unroll
            for (int i = 0; i < 2; i++){
                int idx = tid + i*512;
                int row = idx >> 3, kc = (idx & 7)*8;
                *reinterpret_cast<uint4*>(&Blds[row][kc]) =
                    *reinterpret_cast<const uint4*>(Wt + (size_t)row*KK + k0 + kc);
            }
        } else {
            if (tid < BN*8){
                int row = tid >> 3, kc = (tid & 7)*8;
                *reinterpret_cast<uint4*>(&Blds[row][kc]) =
                    *reinterpret_cast<const uint4*>(Wt + (size_t)row*KK + k0 + kc);
            }
        }
        __syncthreads();
        #pragma unroll
        for (int ks = 0; ks < 2; ks++){
            s16x8 a = *reinterpret_cast<const s16x8*>(&Alds[wr*16 + lane15][ks*32 + kc8]);
            #pragma unroll
            for (int ct = 0; ct < CT; ct++){
                s16x8 b = *reinterpret_cast<const s16x8*>(
                    &Blds[wc*(BN/2) + ct*16 + lane15][ks*32 + kc8]);
                acc[ct] = __builtin_amdgcn_mfma_f32_16x16x32_bf16(a, b, acc[ct], 0,0,0);
            }
        }
        __syncthreads();
    }
    int rb = m0 + wr*16 + ((lane >> 4) << 2);
    #pragma unroll
    for (int ct = 0; ct < CT; ct++){
        int col = wc*(BN/2) + ct*16 + lane15;
        float bv = bias[col];
        #pragma unroll
        for (int r = 0; r < 4; r++){
            int row = rb + r;
            if (row < vc){
                float val = acc[ct][r] + bv;
                if (RELU) val = fmaxf(val, 0.f);
                if (OUT_BF16)
                    reinterpret_cast<ushort_t*>(yout)[(size_t)row*BN + col] = f_to_bf16(val);
                else
                    reinterpret_cast<float*>(yout)[(size_t)row*BN + col] = val;
            }
        }
    }
}

extern "C" void kernel_launch(void* const* d_in, const int* in_sizes, int n_in,
                              void* d_out, int out_size, void* d_ws, size_t ws_size,
                              hipStream_t stream){
    const int*   src   = (const int*)d_in[0];
    const int*   dst   = (const int*)d_in[1];
    const int*   etype = (const int*)d_in[2];
    const float* norm  = (const float*)d_in[3];
    const float* emb   = (const float*)d_in[4];
    const float* V1    = (const float*)d_in[5];
    const float* comp1 = (const float*)d_in[6];
    const float* bias1 = (const float*)d_in[7];
    const float* V2    = (const float*)d_in[8];
    const float* comp2 = (const float*)d_in[9];
    const float* bias2 = (const float*)d_in[10];
    float* out = (float*)d_out;

    char* w = (char*)d_ws;
    auto alloc = [&](size_t bytes) -> char* {
        char* p = w; w += (bytes + 255) & ~(size_t)255; return p;
    };
    int*      offsets = (int*)alloc((NN + 1) * 4);
    int*      counts  = (int*)alloc(NN * 4);
    int*      cursor  = (int*)alloc(NN * 4);
    int*      tot     = (int*)alloc(SC_B * 4);
    uint_t*   msrcet  = (uint_t*)alloc((size_t)EE * 4);
    float*    normA   = (float*)alloc((size_t)EE * 4);
    ushort_t* Wt1     = (ushort_t*)alloc((size_t)HH * KK * 2);
    ushort_t* Wt2     = (ushort_t*)alloc((size_t)OUTD * KK * 2);
    ushort_t* xb      = (ushort_t*)alloc((size_t)NN * HH * 2);
    ushort_t* h       = (ushort_t*)alloc((size_t)NN * HH * 2);
    size_t used  = (size_t)(w - (char*)d_ws);
    size_t avail = ws_size > used ? ws_size - used : 0;
    int chunkN = (int)(avail / ((size_t)KK * 2));
    chunkN &= ~63;
    if (chunkN < 64) chunkN = 64;
    if (chunkN > NN) chunkN = NN;
    ushort_t* agg = (ushort_t*)w;

    // CSR build + payload sort + weight/emb conversion
    zero_i32<<<(NN + 255)/256, 256, 0, stream>>>(counts, NN);
    hist_kernel<<<(EE + 255)/256, 256, 0, stream>>>(dst, counts);
    scan_part<<<SC_B, 256, 0, stream>>>(counts, tot);
    scan_tot<<<1, 64, 0, stream>>>(tot);
    scan_final<<<SC_B, 256, 0, stream>>>(counts, tot, offsets, cursor);
    scatter_kernel<<<(EE + 255)/256, 256, 0, stream>>>(dst, src, etype, norm,
                                                       cursor, msrcet, normA);
    convw_kernel<<<((HH + OUTD)*KK + 255)/256, 256, 0, stream>>>(V1, V2, Wt1, Wt2);
    conv_emb<<<(NN*HH/2 + 255)/256, 256, 0, stream>>>(emb, xb);

    // layer 1: xb (bf16) -> h (bf16, relu)
    for (int v0 = 0; v0 < NN; v0 += chunkN){
        int vc = (NN - v0 < chunkN) ? (NN - v0) : chunkN;
        agg_kernel<<<(vc + 3)/4, 256, 0, stream>>>(
            xb, msrcet, (const int*)normA, offsets, comp1, agg, v0, vc);
        gemm_kernel<HH, true, true><<<(vc + 63)/64, 512, 0, stream>>>(
            agg, Wt1, bias1, h + (size_t)v0 * HH, vc);
    }
    // layer 2: h (bf16) -> out (f32)
    for (int v0 = 0; v0 < NN; v0 += chunkN){
        int vc = (NN - v0 < chunkN) ? (NN - v0) : chunkN;
        agg_kernel<<<(vc + 3)/4, 256, 0, stream>>>(
            h, msrcet, (const int*)normA, offsets, comp2, agg, v0, vc);
        gemm_kernel<OUTD, false, false><<<(vc + 63)/64, 512, 0, stream>>>(
            agg, Wt2, bias2, out + (size_t)v0 * OUTD, vc);
    }
}

// Round 10
// 324.468 us; speedup vs baseline: 1.3582x; 1.1778x over previous
//
#include <hip/hip_runtime.h>
#include <hip/hip_bf16.h>

#define NN 50000
#define EE 600000
#define HH 128
#define OUTD 32
#define RR 64
#define BB 16
#define KK 2048   // BB*HH
#define SC_B ((NN + 1023) / 1024)  // 49 scan chunks

typedef short s16x8 __attribute__((ext_vector_type(8)));
typedef float f32x4 __attribute__((ext_vector_type(4)));
typedef float f32x2 __attribute__((ext_vector_type(2)));
typedef unsigned short ushort_t;
typedef unsigned int uint_t;

__device__ inline ushort_t f_to_bf16(float f){
    __hip_bfloat16 h = __float2bfloat16(f);
    return *reinterpret_cast<ushort_t*>(&h);
}
__device__ inline uint_t pack_bf16x2(float a, float b){
    return (uint_t)f_to_bf16(a) | ((uint_t)f_to_bf16(b) << 16);
}

__global__ void zero_i32(int* p, int n){
    int i = blockIdx.x*256 + threadIdx.x;
    if (i < n) p[i] = 0;
}

__global__ void hist_kernel(const int* __restrict__ dst, int* counts){
    int e = blockIdx.x*256 + threadIdx.x;
    if (e < EE) atomicAdd(&counts[dst[e]], 1);
}

// ---- hierarchical scan: chunk totals -> scan totals -> final ----
__global__ void scan_part(const int* __restrict__ counts, int* __restrict__ tot){
    int b = blockIdx.x, t = threadIdx.x;
    int i0 = b*1024 + t*4;
    int s = 0;
    if (i0 + 3 < NN){
        int4 v = *reinterpret_cast<const int4*>(&counts[i0]);
        s = v.x + v.y + v.z + v.w;
    } else {
        for (int j = 0; j < 4; j++) if (i0 + j < NN) s += counts[i0 + j];
    }
    #pragma unroll
    for (int off = 32; off; off >>= 1) s += __shfl_xor(s, off, 64);
    __shared__ int ws[4];
    if ((t & 63) == 0) ws[t >> 6] = s;
    __syncthreads();
    if (t == 0) tot[b] = ws[0] + ws[1] + ws[2] + ws[3];
}

__global__ void scan_tot(int* tot){  // 1 block, 64 threads (SC_B <= 64)
    int t = threadIdx.x;
    int v = (t < SC_B) ? tot[t] : 0;
    int x = v;
    #pragma unroll
    for (int off = 1; off < 64; off <<= 1){
        int y = __shfl_up(x, off, 64);
        if (t >= off) x += y;
    }
    if (t < SC_B) tot[t] = x - v;  // exclusive base per chunk
}

__global__ void scan_final(const int* __restrict__ counts, const int* __restrict__ tot,
                           int* __restrict__ offsets, int* __restrict__ cursor){
    int b = blockIdx.x, t = threadIdx.x, lane = t & 63, wv = t >> 6;
    int i0 = b*1024 + t*4;
    int v[4]; int s = 0;
    #pragma unroll
    for (int j = 0; j < 4; j++){ v[j] = (i0 + j < NN) ? counts[i0 + j] : 0; s += v[j]; }
    int x = s;
    #pragma unroll
    for (int off = 1; off < 64; off <<= 1){
        int y = __shfl_up(x, off, 64);
        if (lane >= off) x += y;
    }
    __shared__ int ws[4];
    if (lane == 63) ws[wv] = x;
    __syncthreads();
    int pre = tot[b];
    for (int i = 0; i < wv; i++) pre += ws[i];
    int run = pre + x - s;  // exclusive start of this thread's 4 elems
    #pragma unroll
    for (int j = 0; j < 4; j++){
        if (i0 + j < NN){
            cursor[i0 + j] = run;
            offsets[i0 + j + 1] = run + v[j];
        }
        run += v[j];
    }
    if (b == 0 && t == 0) offsets[0] = 0;
}

// scatter dst-sorted edge payload: msrc[r] = src row, netn[r] = norm_bits|etype
// (etype stuffed into norm's 6 low mantissa bits: <=7.5e-6 relative error)
__global__ void scatter_kernel(const int* __restrict__ dst, const int* __restrict__ src,
                               const int* __restrict__ etype, const float* __restrict__ norm,
                               int* cursor, int* __restrict__ msrc, int* __restrict__ netn){
    int e = blockIdx.x*256 + threadIdx.x;
    if (e >= EE) return;
    int d = dst[e];
    int r = atomicAdd(&cursor[d], 1);
    msrc[r] = src[e];
    netn[r] = (__float_as_int(norm[e]) & ~63) | etype[e];
}

// transposed bf16 weights: Wt1[o][k] = V1[k][o] (k = b*H+i), Wt2[o][k] = V2[k][o]
__global__ void convw_kernel(const float* __restrict__ V1, const float* __restrict__ V2,
                             ushort_t* __restrict__ Wt1, ushort_t* __restrict__ Wt2){
    int i = blockIdx.x*256 + threadIdx.x;
    if (i < HH*KK){
        int o = i / KK, k = i % KK;
        Wt1[i] = f_to_bf16(V1[(size_t)k*HH + o]);
    } else {
        int j = i - HH*KK;
        if (j < OUTD*KK){
            int o = j / KK, k = j % KK;
            Wt2[j] = f_to_bf16(V2[(size_t)k*OUTD + o]);
        }
    }
}

__global__ void conv_emb(const float* __restrict__ emb, ushort_t* __restrict__ xb){
    int i = blockIdx.x*256 + threadIdx.x;
    if (i < NN*HH/2){
        float2 f = *reinterpret_cast<const float2*>(emb + 2*(size_t)i);
        *reinterpret_cast<uint_t*>(xb + 2*(size_t)i) = pack_bf16x2(f.x, f.y);
    }
}

// Aggregate: 1 node per wave, 4 waves/block, no LDS/barriers. Per <=64-edge
// chunk: metas in lane registers; 8-deep register ring of coalesced 256B
// x-row loads; consume = 16 v_pk_fma_f32 per edge (dual-f32, comp pairs come
// as consecutive SGPRs from the scalar cache; op_sel broadcasts the x feat).
__global__ __launch_bounds__(256, 8) void agg_kernel(
    const ushort_t* __restrict__ xin, const int* __restrict__ msrc,
    const int* __restrict__ netn, const int* __restrict__ offsets,
    const float* __restrict__ comp, ushort_t* __restrict__ agg,
    int v0, int vc)
{
    int w = threadIdx.x >> 6, lane = threadIdx.x & 63;
    int v = v0 + blockIdx.x*4 + w;
    if (v >= v0 + vc) return;
    int p0 = offsets[v];
    int dd = offsets[v+1] - p0;
    const uint_t* xrow = reinterpret_cast<const uint_t*>(xin);  // row r at xrow + r*64

    // accA[bp] = {agg[2bp], agg[2bp+1]} at feat 2*lane; accB at feat 2*lane+1
    f32x2 accA[8], accB[8];
    #pragma unroll
    for (int bp = 0; bp < 8; bp++){
        accA[bp].x = 0.f; accA[bp].y = 0.f;
        accB[bp].x = 0.f; accB[bp].y = 0.f;
    }

    for (int c0 = 0; c0 < dd; c0 += 64){
        int nc = min(64, dd - c0);
        int li = p0 + c0 + min(lane, nc - 1);
        int mp = msrc[li];      // lane e: src row of edge e
        int nr = netn[li];      // lane e: norm bits | etype
        uint_t xr[8];
        #pragma unroll
        for (int j = 0; j < 8; ++j){
            int sr = __builtin_amdgcn_readlane(mp, min(j, nc - 1));
            xr[j] = xrow[(size_t)sr*64 + lane];
        }
        for (int eb = 0; eb < nc; eb += 8){
            #pragma unroll
            for (int j = 0; j < 8; ++j){
                int e = eb + j;                       // uniform
                int ec = min(e, nc - 1);
                int nb = __builtin_amdgcn_readlane(nr, ec);
                int et = nb & 63;
                float nw = (e < nc) ? __int_as_float(nb & ~63) : 0.f;
                uint_t u = xr[j];
                f32x2 xs;
                xs.x = __uint_as_float(u << 16) * nw;         // feat 2*lane
                xs.y = __uint_as_float(u & 0xffff0000u) * nw; // feat 2*lane+1
                int en = e + 8;
                if (en < nc){                          // uniform branch: refill ring
                    int srn = __builtin_amdgcn_readlane(mp, en);
                    xr[j] = xrow[(size_t)srn*64 + lane];
                }
                const f32x2* cp = reinterpret_cast<const f32x2*>(comp + et*BB);
                #pragma unroll
                for (int bp = 0; bp < 8; bp++){
                    f32x2 c2 = cp[bp];   // {c[2bp], c[2bp+1]} consecutive SGPRs
                    asm("v_pk_fma_f32 %0, %1, %2, %0 op_sel:[0,0,0] op_sel_hi:[1,0,1]"
                        : "+v"(accA[bp]) : "s"(c2), "v"(xs));
                    asm("v_pk_fma_f32 %0, %1, %2, %0 op_sel:[0,1,0] op_sel_hi:[1,1,1]"
                        : "+v"(accB[bp]) : "s"(c2), "v"(xs));
                }
            }
        }
    }
    // store agg row (bf16x2 packed, coalesced 256B per basis)
    uint_t* arow = reinterpret_cast<uint_t*>(agg) + (size_t)(v - v0)*1024 + lane;
    #pragma unroll
    for (int b = 0; b < BB; b++)
        arow[b*64] = pack_bf16x2(accA[b>>1][b&1], accB[b>>1][b&1]);
}

// GEMM: C[m, o] = sum_k A[m,k] * Wt[o,k] (+bias, opt relu). 64xBN tile,
// 512 thr (8 waves: 4 row-tiles x 2 col-halves). A read exactly once.
template<int BN, bool RELU, bool OUT_BF16>
__global__ __launch_bounds__(512, 6) void gemm_kernel(
    const ushort_t* __restrict__ A, const ushort_t* __restrict__ Wt,
    const float* __restrict__ bias, void* __restrict__ yout, int vc)
{
    __shared__ ushort_t Alds[64][72];
    __shared__ ushort_t Blds[BN][72];
    constexpr int CT = BN / 32;        // col-tiles per wave
    int tid = threadIdx.x, lane = tid & 63, lane15 = lane & 15;
    int w = tid >> 6, wr = w >> 1, wc = w & 1;
    int m0 = blockIdx.x * 64;
    int kc8 = (lane >> 4) * 8;

    f32x4 acc[CT];
    #pragma unroll
    for (int ct = 0; ct < CT; ct++)
        #pragma unroll
        for (int j = 0; j < 4; j++) acc[ct][j] = 0.f;

    for (int k0 = 0; k0 < KK; k0 += 64){
        {   // stage A 64x64: exactly one uint4 per thread
            int row = tid >> 3, kc = (tid & 7) * 8;
            uint4 val = make_uint4(0u,0u,0u,0u);
            if (m0 + row < vc)
                val = *reinterpret_cast<const uint4*>(A + (size_t)(m0+row)*KK + k0 + kc);
            *reinterpret_cast<uint4*>(&Alds[row][kc]) = val;
        }
        if (BN == 128){
            #pragma unroll
            for (int i = 0; i < 2; i++){
                int idx = tid + i*512;
                int row = idx >> 3, kc = (idx & 7)*8;
                *reinterpret_cast<uint4*>(&Blds[row][kc]) =
                    *reinterpret_cast<const uint4*>(Wt + (size_t)row*KK + k0 + kc);
            }
        } else {
            if (tid < BN*8){
                int row = tid >> 3, kc = (tid & 7)*8;
                *reinterpret_cast<uint4*>(&Blds[row][kc]) =
                    *reinterpret_cast<const uint4*>(Wt + (size_t)row*KK + k0 + kc);
            }
        }
        __syncthreads();
        #pragma unroll
        for (int ks = 0; ks < 2; ks++){
            s16x8 a = *reinterpret_cast<const s16x8*>(&Alds[wr*16 + lane15][ks*32 + kc8]);
            #pragma unroll
            for (int ct = 0; ct < CT; ct++){
                s16x8 b = *reinterpret_cast<const s16x8*>(
                    &Blds[wc*(BN/2) + ct*16 + lane15][ks*32 + kc8]);
                acc[ct] = __builtin_amdgcn_mfma_f32_16x16x32_bf16(a, b, acc[ct], 0,0,0);
            }
        }
        __syncthreads();
    }
    int rb = m0 + wr*16 + ((lane >> 4) << 2);
    #pragma unroll
    for (int ct = 0; ct < CT; ct++){
        int col = wc*(BN/2) + ct*16 + lane15;
        float bv = bias[col];
        #pragma unroll
        for (int r = 0; r < 4; r++){
            int row = rb + r;
            if (row < vc){
                float val = acc[ct][r] + bv;
                if (RELU) val = fmaxf(val, 0.f);
                if (OUT_BF16)
                    reinterpret_cast<ushort_t*>(yout)[(size_t)row*BN + col] = f_to_bf16(val);
                else
                    reinterpret_cast<float*>(yout)[(size_t)row*BN + col] = val;
            }
        }
    }
}

extern "C" void kernel_launch(void* const* d_in, const int* in_sizes, int n_in,
                              void* d_out, int out_size, void* d_ws, size_t ws_size,
                              hipStream_t stream){
    const int*   src   = (const int*)d_in[0];
    const int*   dst   = (const int*)d_in[1];
    const int*   etype = (const int*)d_in[2];
    const float* norm  = (const float*)d_in[3];
    const float* emb   = (const float*)d_in[4];
    const float* V1    = (const float*)d_in[5];
    const float* comp1 = (const float*)d_in[6];
    const float* bias1 = (const float*)d_in[7];
    const float* V2    = (const float*)d_in[8];
    const float* comp2 = (const float*)d_in[9];
    const float* bias2 = (const float*)d_in[10];
    float* out = (float*)d_out;

    char* w = (char*)d_ws;
    auto alloc = [&](size_t bytes) -> char* {
        char* p = w; w += (bytes + 255) & ~(size_t)255; return p;
    };
    int*      offsets = (int*)alloc((NN + 1) * 4);
    int*      counts  = (int*)alloc(NN * 4);
    int*      cursor  = (int*)alloc(NN * 4);
    int*      tot     = (int*)alloc(SC_B * 4);
    int*      msrc    = (int*)alloc((size_t)EE * 4);
    int*      netn    = (int*)alloc((size_t)EE * 4);
    ushort_t* Wt1     = (ushort_t*)alloc((size_t)HH * KK * 2);
    ushort_t* Wt2     = (ushort_t*)alloc((size_t)OUTD * KK * 2);
    ushort_t* xb      = (ushort_t*)alloc((size_t)NN * HH * 2);
    ushort_t* h       = (ushort_t*)alloc((size_t)NN * HH * 2);
    size_t used  = (size_t)(w - (char*)d_ws);
    size_t avail = ws_size > used ? ws_size - used : 0;
    int chunkN = (int)(avail / ((size_t)KK * 2));
    chunkN &= ~63;
    if (chunkN < 64) chunkN = 64;
    if (chunkN > NN) chunkN = NN;
    ushort_t* agg = (ushort_t*)w;

    // CSR build + payload sort + weight/emb conversion
    zero_i32<<<(NN + 255)/256, 256, 0, stream>>>(counts, NN);
    hist_kernel<<<(EE + 255)/256, 256, 0, stream>>>(dst, counts);
    scan_part<<<SC_B, 256, 0, stream>>>(counts, tot);
    scan_tot<<<1, 64, 0, stream>>>(tot);
    scan_final<<<SC_B, 256, 0, stream>>>(counts, tot, offsets, cursor);
    scatter_kernel<<<(EE + 255)/256, 256, 0, stream>>>(dst, src, etype, norm,
                                                       cursor, msrc, netn);
    convw_kernel<<<((HH + OUTD)*KK + 255)/256, 256, 0, stream>>>(V1, V2, Wt1, Wt2);
    conv_emb<<<(NN*HH/2 + 255)/256, 256, 0, stream>>>(emb, xb);

    // layer 1: xb (bf16) -> h (bf16, relu)
    for (int v0 = 0; v0 < NN; v0 += chunkN){
        int vc = (NN - v0 < chunkN) ? (NN - v0) : chunkN;
        agg_kernel<<<(vc + 3)/4, 256, 0, stream>>>(
            xb, msrc, netn, offsets, comp1, agg, v0, vc);
        gemm_kernel<HH, true, true><<<(vc + 63)/64, 512, 0, stream>>>(
            agg, Wt1, bias1, h + (size_t)v0 * HH, vc);
    }
    // layer 2: h (bf16) -> out (f32)
    for (int v0 = 0; v0 < NN; v0 += chunkN){
        int vc = (NN - v0 < chunkN) ? (NN - v0) : chunkN;
        agg_kernel<<<(vc + 3)/4, 256, 0, stream>>>(
            h, msrc, netn, offsets, comp2, agg, v0, vc);
        gemm_kernel<OUTD, false, false><<<(vc + 63)/64, 512, 0, stream>>>(
            agg, Wt2, bias2, out + (size_t)v0 * OUTD, vc);
    }
}

// Round 11
// 319.128 us; speedup vs baseline: 1.3809x; 1.0167x over previous
//
#include <hip/hip_runtime.h>
#include <hip/hip_bf16.h>

#define NN 50000
#define EE 600000
#define HH 128
#define OUTD 32
#define RR 64
#define BB 16
#define KK 2048   // BB*HH
#define SC_B ((NN + 1023) / 1024)  // 49 scan chunks

typedef short s16x8 __attribute__((ext_vector_type(8)));
typedef float f32x4 __attribute__((ext_vector_type(4)));
typedef float f32x2 __attribute__((ext_vector_type(2)));
typedef unsigned short ushort_t;
typedef unsigned int uint_t;
typedef __attribute__((address_space(3))) uint_t lds_u32;
typedef const __attribute__((address_space(1))) uint_t glb_u32;

__device__ inline ushort_t f_to_bf16(float f){
    __hip_bfloat16 h = __float2bfloat16(f);
    return *reinterpret_cast<ushort_t*>(&h);
}
__device__ inline uint_t pack_bf16x2(float a, float b){
    return (uint_t)f_to_bf16(a) | ((uint_t)f_to_bf16(b) << 16);
}

__global__ void zero_i32(int* p, int n){
    int i = blockIdx.x*256 + threadIdx.x;
    if (i < n) p[i] = 0;
}

__global__ void hist_kernel(const int* __restrict__ dst, int* counts){
    int e = blockIdx.x*256 + threadIdx.x;
    if (e < EE) atomicAdd(&counts[dst[e]], 1);
}

// ---- hierarchical scan: chunk totals -> scan totals -> final ----
__global__ void scan_part(const int* __restrict__ counts, int* __restrict__ tot){
    int b = blockIdx.x, t = threadIdx.x;
    int i0 = b*1024 + t*4;
    int s = 0;
    if (i0 + 3 < NN){
        int4 v = *reinterpret_cast<const int4*>(&counts[i0]);
        s = v.x + v.y + v.z + v.w;
    } else {
        for (int j = 0; j < 4; j++) if (i0 + j < NN) s += counts[i0 + j];
    }
    #pragma unroll
    for (int off = 32; off; off >>= 1) s += __shfl_xor(s, off, 64);
    __shared__ int ws[4];
    if ((t & 63) == 0) ws[t >> 6] = s;
    __syncthreads();
    if (t == 0) tot[b] = ws[0] + ws[1] + ws[2] + ws[3];
}

__global__ void scan_tot(int* tot){  // 1 block, 64 threads (SC_B <= 64)
    int t = threadIdx.x;
    int v = (t < SC_B) ? tot[t] : 0;
    int x = v;
    #pragma unroll
    for (int off = 1; off < 64; off <<= 1){
        int y = __shfl_up(x, off, 64);
        if (t >= off) x += y;
    }
    if (t < SC_B) tot[t] = x - v;  // exclusive base per chunk
}

__global__ void scan_final(const int* __restrict__ counts, const int* __restrict__ tot,
                           int* __restrict__ offsets, int* __restrict__ cursor){
    int b = blockIdx.x, t = threadIdx.x, lane = t & 63, wv = t >> 6;
    int i0 = b*1024 + t*4;
    int v[4]; int s = 0;
    #pragma unroll
    for (int j = 0; j < 4; j++){ v[j] = (i0 + j < NN) ? counts[i0 + j] : 0; s += v[j]; }
    int x = s;
    #pragma unroll
    for (int off = 1; off < 64; off <<= 1){
        int y = __shfl_up(x, off, 64);
        if (lane >= off) x += y;
    }
    __shared__ int ws[4];
    if (lane == 63) ws[wv] = x;
    __syncthreads();
    int pre = tot[b];
    for (int i = 0; i < wv; i++) pre += ws[i];
    int run = pre + x - s;  // exclusive start of this thread's 4 elems
    #pragma unroll
    for (int j = 0; j < 4; j++){
        if (i0 + j < NN){
            cursor[i0 + j] = run;
            offsets[i0 + j + 1] = run + v[j];
        }
        run += v[j];
    }
    if (b == 0 && t == 0) offsets[0] = 0;
}

// scatter dst-sorted edge payload: msrc[r] = src row, netn[r] = norm_bits|etype
// (etype stuffed into norm's 6 low mantissa bits: <=7.5e-6 relative error)
__global__ void scatter_kernel(const int* __restrict__ dst, const int* __restrict__ src,
                               const int* __restrict__ etype, const float* __restrict__ norm,
                               int* cursor, int* __restrict__ msrc, int* __restrict__ netn){
    int e = blockIdx.x*256 + threadIdx.x;
    if (e >= EE) return;
    int d = dst[e];
    int r = atomicAdd(&cursor[d], 1);
    msrc[r] = src[e];
    netn[r] = (__float_as_int(norm[e]) & ~63) | etype[e];
}

// transposed bf16 weights: Wt1[o][k] = V1[k][o] (k = b*H+i), Wt2[o][k] = V2[k][o]
__global__ void convw_kernel(const float* __restrict__ V1, const float* __restrict__ V2,
                             ushort_t* __restrict__ Wt1, ushort_t* __restrict__ Wt2){
    int i = blockIdx.x*256 + threadIdx.x;
    if (i < HH*KK){
        int o = i / KK, k = i % KK;
        Wt1[i] = f_to_bf16(V1[(size_t)k*HH + o]);
    } else {
        int j = i - HH*KK;
        if (j < OUTD*KK){
            int o = j / KK, k = j % KK;
            Wt2[j] = f_to_bf16(V2[(size_t)k*OUTD + o]);
        }
    }
}

__global__ void conv_emb(const float* __restrict__ emb, ushort_t* __restrict__ xb){
    int i = blockIdx.x*256 + threadIdx.x;
    if (i < NN*HH/2){
        float2 f = *reinterpret_cast<const float2*>(emb + 2*(size_t)i);
        *reinterpret_cast<uint_t*>(xb + 2*(size_t)i) = pack_bf16x2(f.x, f.y);
    }
}

// Aggregate: 1 node per wave, 4 waves/block, no LDS/barriers. Per <=64-edge
// chunk: metas in lane registers; 8-deep register ring of coalesced 256B
// x-row loads; consume = 16 v_pk_fma_f32 per edge (dual-f32; comp pairs come
// as consecutive SGPRs from the scalar cache; op_sel broadcasts the x feat).
__global__ __launch_bounds__(256, 8) void agg_kernel(
    const ushort_t* __restrict__ xin, const int* __restrict__ msrc,
    const int* __restrict__ netn, const int* __restrict__ offsets,
    const float* __restrict__ comp, ushort_t* __restrict__ agg,
    int v0, int vc)
{
    int w = threadIdx.x >> 6, lane = threadIdx.x & 63;
    int v = v0 + blockIdx.x*4 + w;
    if (v >= v0 + vc) return;
    int p0 = offsets[v];
    int dd = offsets[v+1] - p0;
    const uint_t* xrow = reinterpret_cast<const uint_t*>(xin);  // row r at xrow + r*64

    // accA[bp] = {agg[2bp], agg[2bp+1]} at feat 2*lane; accB at feat 2*lane+1
    f32x2 accA[8], accB[8];
    #pragma unroll
    for (int bp = 0; bp < 8; bp++){
        accA[bp].x = 0.f; accA[bp].y = 0.f;
        accB[bp].x = 0.f; accB[bp].y = 0.f;
    }

    for (int c0 = 0; c0 < dd; c0 += 64){
        int nc = min(64, dd - c0);
        int li = p0 + c0 + min(lane, nc - 1);
        int mp = msrc[li];      // lane e: src row of edge e
        int nr = netn[li];      // lane e: norm bits | etype
        uint_t xr[8];
        #pragma unroll
        for (int j = 0; j < 8; ++j){
            int sr = __builtin_amdgcn_readlane(mp, min(j, nc - 1));
            xr[j] = xrow[(size_t)sr*64 + lane];
        }
        for (int eb = 0; eb < nc; eb += 8){
            #pragma unroll
            for (int j = 0; j < 8; ++j){
                int e = eb + j;                       // uniform
                int ec = min(e, nc - 1);
                int nb = __builtin_amdgcn_readlane(nr, ec);
                int et = nb & 63;
                float nw = (e < nc) ? __int_as_float(nb & ~63) : 0.f;
                uint_t u = xr[j];
                f32x2 xs;
                xs.x = __uint_as_float(u << 16) * nw;         // feat 2*lane
                xs.y = __uint_as_float(u & 0xffff0000u) * nw; // feat 2*lane+1
                int en = e + 8;
                if (en < nc){                          // uniform branch: refill ring
                    int srn = __builtin_amdgcn_readlane(mp, en);
                    xr[j] = xrow[(size_t)srn*64 + lane];
                }
                const f32x2* cp = reinterpret_cast<const f32x2*>(comp + et*BB);
                #pragma unroll
                for (int bp = 0; bp < 8; bp++){
                    f32x2 c2 = cp[bp];   // {c[2bp], c[2bp+1]} consecutive SGPRs
                    asm("v_pk_fma_f32 %0, %1, %2, %0 op_sel:[0,0,0] op_sel_hi:[1,0,1]"
                        : "+v"(accA[bp]) : "s"(c2), "v"(xs));
                    asm("v_pk_fma_f32 %0, %1, %2, %0 op_sel:[0,1,0] op_sel_hi:[1,1,1]"
                        : "+v"(accB[bp]) : "s"(c2), "v"(xs));
                }
            }
        }
    }
    // store agg row (bf16x2 packed, coalesced 256B per basis)
    uint_t* arow = reinterpret_cast<uint_t*>(agg) + (size_t)(v - v0)*1024 + lane;
    #pragma unroll
    for (int b = 0; b < BB; b++)
        arow[b*64] = pack_bf16x2(accA[b>>1][b&1], accB[b>>1][b&1]);
}

// GEMM: C[m, o] = sum_k A[m,k] * Wt[o,k] (+bias, opt relu). 64xBN tile, 512 thr
// (8 waves: 4 row-tiles x 2 col-halves). Double-buffered global_load_lds
// staging (width 16) with chunk-XOR swizzle (source chunk j^(row&7) -> linear
// LDS; reads re-apply the XOR). One barrier per k-step; next tile's DMAs are
// in flight across the compute phase.
template<int BN, bool RELU, bool OUT_BF16>
__global__ __launch_bounds__(512, 6) void gemm_kernel(
    const ushort_t* __restrict__ A, const ushort_t* __restrict__ Wt,
    const float* __restrict__ bias, void* __restrict__ yout, int vc)
{
    __shared__ __align__(16) char Ald[2][64*128];
    __shared__ __align__(16) char Bld[2][BN*128];
    constexpr int CT = BN / 32;        // col-tiles per wave
    int tid = threadIdx.x, lane = tid & 63, lane15 = lane & 15;
    int w = tid >> 6, wr = w >> 1, wc = w & 1;
    int m0 = blockIdx.x * 64;

    // staging sources (per lane): row = tid>>3, LDS chunk j = tid&7,
    // global chunk = j ^ (row&7). OOB A rows clamped (results discarded).
    int sr_ = tid >> 3, sj_ = (tid & 7) ^ (sr_ & 7);
    const ushort_t* agp = A + (size_t)(m0 + min(sr_, vc - 1))*KK + sj_*8;
    const ushort_t* bgp0 = Wt + (size_t)sr_*KK + sj_*8;
    const ushort_t* bgp1 = Wt + (size_t)(64 + sr_)*KK + sj_*8;  // used only BN=128

    auto stage = [&](int buf){
        __builtin_amdgcn_global_load_lds((glb_u32*)agp,
            (lds_u32*)(&Ald[buf][w*1024]), 16, 0, 0);
        if constexpr (BN == 128){
            __builtin_amdgcn_global_load_lds((glb_u32*)bgp0,
                (lds_u32*)(&Bld[buf][w*1024]), 16, 0, 0);
            __builtin_amdgcn_global_load_lds((glb_u32*)bgp1,
                (lds_u32*)(&Bld[buf][8192 + w*1024]), 16, 0, 0);
            bgp1 += 64;
        } else {
            if (w < 4)
                __builtin_amdgcn_global_load_lds((glb_u32*)bgp0,
                    (lds_u32*)(&Bld[buf][w*1024]), 16, 0, 0);
        }
        agp += 64; bgp0 += 64;
    };

    f32x4 acc[CT];
    #pragma unroll
    for (int ct = 0; ct < CT; ct++)
        #pragma unroll
        for (int j = 0; j < 4; j++) acc[ct][j] = 0.f;

    int arow = wr*16 + lane15;
    auto compute = [&](int buf){
        #pragma unroll
        for (int ks = 0; ks < 2; ks++){
            int csw = (ks*4 + (lane >> 4)) ^ (lane15 & 7);   // swizzled chunk
            s16x8 a = *reinterpret_cast<const s16x8*>(&Ald[buf][arow*128 + csw*16]);
            #pragma unroll
            for (int ct = 0; ct < CT; ct++){
                int brow = wc*(BN/2) + ct*16 + lane15;
                s16x8 b = *reinterpret_cast<const s16x8*>(&Bld[buf][brow*128 + csw*16]);
                acc[ct] = __builtin_amdgcn_mfma_f32_16x16x32_bf16(a, b, acc[ct], 0,0,0);
            }
        }
    };

    stage(0);
    __syncthreads();
    for (int t = 0; t < KK/64; t += 2){
        if (t + 1 < KK/64) stage(1);
        compute(0);
        __syncthreads();
        if (t + 2 < KK/64) stage(0);
        compute(1);
        __syncthreads();
    }

    int rb = m0 + wr*16 + ((lane >> 4) << 2);
    #pragma unroll
    for (int ct = 0; ct < CT; ct++){
        int col = wc*(BN/2) + ct*16 + lane15;
        float bv = bias[col];
        #pragma unroll
        for (int r = 0; r < 4; r++){
            int row = rb + r;
            if (row < vc){
                float val = acc[ct][r] + bv;
                if (RELU) val = fmaxf(val, 0.f);
                if (OUT_BF16)
                    reinterpret_cast<ushort_t*>(yout)[(size_t)row*BN + col] = f_to_bf16(val);
                else
                    reinterpret_cast<float*>(yout)[(size_t)row*BN + col] = val;
            }
        }
    }
}

extern "C" void kernel_launch(void* const* d_in, const int* in_sizes, int n_in,
                              void* d_out, int out_size, void* d_ws, size_t ws_size,
                              hipStream_t stream){
    const int*   src   = (const int*)d_in[0];
    const int*   dst   = (const int*)d_in[1];
    const int*   etype = (const int*)d_in[2];
    const float* norm  = (const float*)d_in[3];
    const float* emb   = (const float*)d_in[4];
    const float* V1    = (const float*)d_in[5];
    const float* comp1 = (const float*)d_in[6];
    const float* bias1 = (const float*)d_in[7];
    const float* V2    = (const float*)d_in[8];
    const float* comp2 = (const float*)d_in[9];
    const float* bias2 = (const float*)d_in[10];
    float* out = (float*)d_out;

    char* w = (char*)d_ws;
    auto alloc = [&](size_t bytes) -> char* {
        char* p = w; w += (bytes + 255) & ~(size_t)255; return p;
    };
    int*      offsets = (int*)alloc((NN + 1) * 4);
    int*      counts  = (int*)alloc(NN * 4);
    int*      cursor  = (int*)alloc(NN * 4);
    int*      tot     = (int*)alloc(SC_B * 4);
    int*      msrc    = (int*)alloc((size_t)EE * 4);
    int*      netn    = (int*)alloc((size_t)EE * 4);
    ushort_t* Wt1     = (ushort_t*)alloc((size_t)HH * KK * 2);
    ushort_t* Wt2     = (ushort_t*)alloc((size_t)OUTD * KK * 2);
    ushort_t* xb      = (ushort_t*)alloc((size_t)NN * HH * 2);
    ushort_t* h       = (ushort_t*)alloc((size_t)NN * HH * 2);
    size_t used  = (size_t)(w - (char*)d_ws);
    size_t avail = ws_size > used ? ws_size - used : 0;
    int chunkN = (int)(avail / ((size_t)KK * 2));
    chunkN &= ~63;
    if (chunkN < 64) chunkN = 64;
    if (chunkN > NN) chunkN = NN;
    ushort_t* agg = (ushort_t*)w;

    // CSR build + payload sort + weight/emb conversion
    zero_i32<<<(NN + 255)/256, 256, 0, stream>>>(counts, NN);
    hist_kernel<<<(EE + 255)/256, 256, 0, stream>>>(dst, counts);
    scan_part<<<SC_B, 256, 0, stream>>>(counts, tot);
    scan_tot<<<1, 64, 0, stream>>>(tot);
    scan_final<<<SC_B, 256, 0, stream>>>(counts, tot, offsets, cursor);
    scatter_kernel<<<(EE + 255)/256, 256, 0, stream>>>(dst, src, etype, norm,
                                                       cursor, msrc, netn);
    convw_kernel<<<((HH + OUTD)*KK + 255)/256, 256, 0, stream>>>(V1, V2, Wt1, Wt2);
    conv_emb<<<(NN*HH/2 + 255)/256, 256, 0, stream>>>(emb, xb);

    // layer 1: xb (bf16) -> h (bf16, relu)
    for (int v0 = 0; v0 < NN; v0 += chunkN){
        int vc = (NN - v0 < chunkN) ? (NN - v0) : chunkN;
        agg_kernel<<<(vc + 3)/4, 256, 0, stream>>>(
            xb, msrc, netn, offsets, comp1, agg, v0, vc);
        gemm_kernel<HH, true, true><<<(vc + 63)/64, 512, 0, stream>>>(
            agg, Wt1, bias1, h + (size_t)v0 * HH, vc);
    }
    // layer 2: h (bf16) -> out (f32)
    for (int v0 = 0; v0 < NN; v0 += chunkN){
        int vc = (NN - v0 < chunkN) ? (NN - v0) : chunkN;
        agg_kernel<<<(vc + 3)/4, 256, 0, stream>>>(
            h, msrc, netn, offsets, comp2, agg, v0, vc);
        gemm_kernel<OUTD, false, false><<<(vc + 63)/64, 512, 0, stream>>>(
            agg, Wt2, bias2, out + (size_t)v0 * OUTD, vc);
    }
}

// Round 12
// 310.096 us; speedup vs baseline: 1.4211x; 1.0291x over previous
//
#include <hip/hip_runtime.h>
#include <hip/hip_bf16.h>

#define NN 50000
#define EE 600000
#define HH 128
#define OUTD 32
#define RR 64
#define BB 16
#define KK 2048   // BB*HH
#define SC_B ((NN + 1023) / 1024)  // 49 scan chunks

typedef short s16x8 __attribute__((ext_vector_type(8)));
typedef float f32x4 __attribute__((ext_vector_type(4)));
typedef float f32x2 __attribute__((ext_vector_type(2)));
typedef unsigned short ushort_t;
typedef unsigned int uint_t;
typedef __attribute__((address_space(3))) uint_t lds_u32;
typedef const __attribute__((address_space(1))) uint_t glb_u32;

__device__ inline ushort_t f_to_bf16(float f){
    __hip_bfloat16 h = __float2bfloat16(f);
    return *reinterpret_cast<ushort_t*>(&h);
}
__device__ inline uint_t pack_bf16x2(float a, float b){
    return (uint_t)f_to_bf16(a) | ((uint_t)f_to_bf16(b) << 16);
}

__global__ void zero_i32(int* p, int n){
    int i = blockIdx.x*256 + threadIdx.x;
    if (i < n) p[i] = 0;
}

__global__ void hist_kernel(const int* __restrict__ dst, int* counts){
    int e = blockIdx.x*256 + threadIdx.x;
    if (e < EE) atomicAdd(&counts[dst[e]], 1);
}

// ---- hierarchical scan: chunk totals -> scan totals -> final ----
__global__ void scan_part(const int* __restrict__ counts, int* __restrict__ tot){
    int b = blockIdx.x, t = threadIdx.x;
    int i0 = b*1024 + t*4;
    int s = 0;
    if (i0 + 3 < NN){
        int4 v = *reinterpret_cast<const int4*>(&counts[i0]);
        s = v.x + v.y + v.z + v.w;
    } else {
        for (int j = 0; j < 4; j++) if (i0 + j < NN) s += counts[i0 + j];
    }
    #pragma unroll
    for (int off = 32; off; off >>= 1) s += __shfl_xor(s, off, 64);
    __shared__ int ws[4];
    if ((t & 63) == 0) ws[t >> 6] = s;
    __syncthreads();
    if (t == 0) tot[b] = ws[0] + ws[1] + ws[2] + ws[3];
}

__global__ void scan_tot(int* tot){  // 1 block, 64 threads (SC_B <= 64)
    int t = threadIdx.x;
    int v = (t < SC_B) ? tot[t] : 0;
    int x = v;
    #pragma unroll
    for (int off = 1; off < 64; off <<= 1){
        int y = __shfl_up(x, off, 64);
        if (t >= off) x += y;
    }
    if (t < SC_B) tot[t] = x - v;  // exclusive base per chunk
}

__global__ void scan_final(const int* __restrict__ counts, const int* __restrict__ tot,
                           int* __restrict__ offsets, int* __restrict__ cursor){
    int b = blockIdx.x, t = threadIdx.x, lane = t & 63, wv = t >> 6;
    int i0 = b*1024 + t*4;
    int v[4]; int s = 0;
    #pragma unroll
    for (int j = 0; j < 4; j++){ v[j] = (i0 + j < NN) ? counts[i0 + j] : 0; s += v[j]; }
    int x = s;
    #pragma unroll
    for (int off = 1; off < 64; off <<= 1){
        int y = __shfl_up(x, off, 64);
        if (lane >= off) x += y;
    }
    __shared__ int ws[4];
    if (lane == 63) ws[wv] = x;
    __syncthreads();
    int pre = tot[b];
    for (int i = 0; i < wv; i++) pre += ws[i];
    int run = pre + x - s;  // exclusive start of this thread's 4 elems
    #pragma unroll
    for (int j = 0; j < 4; j++){
        if (i0 + j < NN){
            cursor[i0 + j] = run;
            offsets[i0 + j + 1] = run + v[j];
        }
        run += v[j];
    }
    if (b == 0 && t == 0) offsets[0] = 0;
}

// scatter dst-sorted edge payload: msrc[r] = src row, netn[r] = norm_bits|etype
// (etype stuffed into norm's 6 low mantissa bits: <=7.5e-6 relative error)
__global__ void scatter_kernel(const int* __restrict__ dst, const int* __restrict__ src,
                               const int* __restrict__ etype, const float* __restrict__ norm,
                               int* cursor, int* __restrict__ msrc, int* __restrict__ netn){
    int e = blockIdx.x*256 + threadIdx.x;
    if (e >= EE) return;
    int d = dst[e];
    int r = atomicAdd(&cursor[d], 1);
    msrc[r] = src[e];
    netn[r] = (__float_as_int(norm[e]) & ~63) | etype[e];
}

// transposed bf16 weights: Wt1[o][k] = V1[k][o] (k = b*H+i), Wt2[o][k] = V2[k][o]
__global__ void convw_kernel(const float* __restrict__ V1, const float* __restrict__ V2,
                             ushort_t* __restrict__ Wt1, ushort_t* __restrict__ Wt2){
    int i = blockIdx.x*256 + threadIdx.x;
    if (i < HH*KK){
        int o = i / KK, k = i % KK;
        Wt1[i] = f_to_bf16(V1[(size_t)k*HH + o]);
    } else {
        int j = i - HH*KK;
        if (j < OUTD*KK){
            int o = j / KK, k = j % KK;
            Wt2[j] = f_to_bf16(V2[(size_t)k*OUTD + o]);
        }
    }
}

__global__ void conv_emb(const float* __restrict__ emb, ushort_t* __restrict__ xb){
    int i = blockIdx.x*256 + threadIdx.x;
    if (i < NN*HH/2){
        float2 f = *reinterpret_cast<const float2*>(emb + 2*(size_t)i);
        *reinterpret_cast<uint_t*>(xb + 2*(size_t)i) = pack_bf16x2(f.x, f.y);
    }
}

// Aggregate: 1 node per wave, 4 waves/block, no LDS/barriers. Per <=64-edge
// chunk: metas in lane registers; 8-deep register ring of coalesced 256B
// x-row loads; consume = 16 v_pk_fma_f32 per edge (dual-f32; comp pairs come
// as consecutive SGPRs from the scalar cache; op_sel broadcasts the x feat).
__global__ __launch_bounds__(256, 8) void agg_kernel(
    const ushort_t* __restrict__ xin, const int* __restrict__ msrc,
    const int* __restrict__ netn, const int* __restrict__ offsets,
    const float* __restrict__ comp, ushort_t* __restrict__ agg,
    int v0, int vc)
{
    int w = threadIdx.x >> 6, lane = threadIdx.x & 63;
    int v = v0 + blockIdx.x*4 + w;
    if (v >= v0 + vc) return;
    int p0 = offsets[v];
    int dd = offsets[v+1] - p0;
    const uint_t* xrow = reinterpret_cast<const uint_t*>(xin);  // row r at xrow + r*64

    // accA[bp] = {agg[2bp], agg[2bp+1]} at feat 2*lane; accB at feat 2*lane+1
    f32x2 accA[8], accB[8];
    #pragma unroll
    for (int bp = 0; bp < 8; bp++){
        accA[bp].x = 0.f; accA[bp].y = 0.f;
        accB[bp].x = 0.f; accB[bp].y = 0.f;
    }

    for (int c0 = 0; c0 < dd; c0 += 64){
        int nc = min(64, dd - c0);
        int li = p0 + c0 + min(lane, nc - 1);
        int mp = msrc[li];      // lane e: src row of edge e
        int nr = netn[li];      // lane e: norm bits | etype
        uint_t xr[8];
        #pragma unroll
        for (int j = 0; j < 8; ++j){
            int sr = __builtin_amdgcn_readlane(mp, min(j, nc - 1));
            xr[j] = xrow[(size_t)sr*64 + lane];
        }
        for (int eb = 0; eb < nc; eb += 8){
            #pragma unroll
            for (int j = 0; j < 8; ++j){
                int e = eb + j;                       // uniform
                int ec = min(e, nc - 1);
                int nb = __builtin_amdgcn_readlane(nr, ec);
                int et = nb & 63;
                float nw = (e < nc) ? __int_as_float(nb & ~63) : 0.f;
                uint_t u = xr[j];
                f32x2 xs;
                xs.x = __uint_as_float(u << 16) * nw;         // feat 2*lane
                xs.y = __uint_as_float(u & 0xffff0000u) * nw; // feat 2*lane+1
                int en = e + 8;
                if (en < nc){                          // uniform branch: refill ring
                    int srn = __builtin_amdgcn_readlane(mp, en);
                    xr[j] = xrow[(size_t)srn*64 + lane];
                }
                const f32x2* cp = reinterpret_cast<const f32x2*>(comp + et*BB);
                #pragma unroll
                for (int bp = 0; bp < 8; bp++){
                    f32x2 c2 = cp[bp];   // {c[2bp], c[2bp+1]} consecutive SGPRs
                    asm("v_pk_fma_f32 %0, %1, %2, %0 op_sel:[0,0,0] op_sel_hi:[1,0,1]"
                        : "+v"(accA[bp]) : "s"(c2), "v"(xs));
                    asm("v_pk_fma_f32 %0, %1, %2, %0 op_sel:[0,1,0] op_sel_hi:[1,1,1]"
                        : "+v"(accB[bp]) : "s"(c2), "v"(xs));
                }
            }
        }
    }
    // store agg row (bf16x2 packed, coalesced 256B per basis)
    uint_t* arow = reinterpret_cast<uint_t*>(agg) + (size_t)(v - v0)*1024 + lane;
    #pragma unroll
    for (int b = 0; b < BB; b++)
        arow[b*64] = pack_bf16x2(accA[b>>1][b&1], accB[b>>1][b&1]);
}

// GEMM: C[m, o] = sum_k A[m,k] * Wt[o,k] (+bias, opt relu). 128xBN tile, 512
// thr. BN=128: wave = 32 rows x 64 cols (16 MFMAs/phase). BN=32: wave = 16
// rows x 32 cols. Double-buffered global_load_lds staging w/ chunk-XOR
// swizzle; COUNTED vmcnt at a raw s_barrier so prefetch loads stay in flight
// across the barrier (never drained to 0 in the main loop).
template<int BN, bool RELU, bool OUT_BF16>
__global__ __launch_bounds__(512, 4) void gemm_kernel(
    const ushort_t* __restrict__ A, const ushort_t* __restrict__ Wt,
    const float* __restrict__ bias, void* __restrict__ yout, int vc)
{
    __shared__ __align__(16) char Ald[2][128*128];
    __shared__ __align__(16) char Bld[2][BN*128];
    constexpr int RT = (BN == 128) ? 2 : 1;   // 16-row subtiles per wave
    constexpr int CT = (BN == 128) ? 4 : 2;   // 16-col subtiles per wave
    constexpr int NT = KK / 64;               // 32 phases
    int tid = threadIdx.x, lane = tid & 63, lane15 = lane & 15;
    int w = tid >> 6;
    int wrbase = (BN == 128) ? (w >> 1)*32 : w*16;
    int wcbase = (BN == 128) ? (w & 1)*64 : 0;
    int m0 = blockIdx.x * 128;

    // staging addresses: DMA d of wave w covers tile rows (w*2+d)*8 .. +7.
    // lane -> row ra = base + (lane>>3), LDS chunk j = lane&7, global chunk
    // j ^ (ra&7) (XOR swizzle; reads re-apply). OOB A rows clamped (discarded).
    int rl = lane >> 3, jl = lane & 7;
    int ra0 = w*2*8 + rl,  ra1 = (w*2+1)*8 + rl;
    const ushort_t* agp0 = A + (size_t)(m0 + min(ra0, vc-1))*KK + ((jl ^ (ra0 & 7))*8);
    const ushort_t* agp1 = A + (size_t)(m0 + min(ra1, vc-1))*KK + ((jl ^ (ra1 & 7))*8);
    const ushort_t* bgp0;
    const ushort_t* bgp1;
    if (BN == 128){
        bgp0 = Wt + (size_t)ra0*KK + ((jl ^ (ra0 & 7))*8);
        bgp1 = Wt + (size_t)ra1*KK + ((jl ^ (ra1 & 7))*8);
    } else {
        int rb = w*8 + rl;  // valid for w<4
        bgp0 = Wt + (size_t)min(rb, BN-1)*KK + ((jl ^ (rb & 7))*8);
        bgp1 = nullptr;
    }

    auto stage = [&](int buf){
        __builtin_amdgcn_global_load_lds((glb_u32*)agp0,
            (lds_u32*)(&Ald[buf][(w*2+0)*1024]), 16, 0, 0);
        __builtin_amdgcn_global_load_lds((glb_u32*)agp1,
            (lds_u32*)(&Ald[buf][(w*2+1)*1024]), 16, 0, 0);
        agp0 += 64; agp1 += 64;
        if constexpr (BN == 128){
            __builtin_amdgcn_global_load_lds((glb_u32*)bgp0,
                (lds_u32*)(&Bld[buf][(w*2+0)*1024]), 16, 0, 0);
            __builtin_amdgcn_global_load_lds((glb_u32*)bgp1,
                (lds_u32*)(&Bld[buf][(w*2+1)*1024]), 16, 0, 0);
            bgp0 += 64; bgp1 += 64;
        } else {
            if (w < 4){
                __builtin_amdgcn_global_load_lds((glb_u32*)bgp0,
                    (lds_u32*)(&Bld[buf][w*1024]), 16, 0, 0);
                bgp0 += 64;
            }
        }
    };

    f32x4 acc[RT][CT];
    #pragma unroll
    for (int t = 0; t < RT; t++)
        #pragma unroll
        for (int ct = 0; ct < CT; ct++)
            #pragma unroll
            for (int j = 0; j < 4; j++) acc[t][ct][j] = 0.f;

    auto compute = [&](int buf){
        #pragma unroll
        for (int ks = 0; ks < 2; ks++){
            int csw = (ks*4 + (lane >> 4)) ^ (lane15 & 7);   // swizzled chunk
            #pragma unroll
            for (int t = 0; t < RT; t++){
                int arow = wrbase + t*16 + lane15;
                s16x8 a = *reinterpret_cast<const s16x8*>(&Ald[buf][arow*128 + csw*16]);
                #pragma unroll
                for (int ct = 0; ct < CT; ct++){
                    int brow = wcbase + ct*16 + lane15;
                    s16x8 b = *reinterpret_cast<const s16x8*>(&Bld[buf][brow*128 + csw*16]);
                    acc[t][ct] = __builtin_amdgcn_mfma_f32_16x16x32_bf16(a, b, acc[t][ct], 0,0,0);
                }
            }
        }
    };

    stage(0);
    for (int t = 0; t < NT; ++t){
        int cur = t & 1;
        if (t + 1 < NT){
            stage(cur ^ 1);
            // counted wait: only the previous phase's loads must have landed
            if (BN == 128)       asm volatile("s_waitcnt vmcnt(4)" ::: "memory");
            else if (w < 4)      asm volatile("s_waitcnt vmcnt(3)" ::: "memory");
            else                 asm volatile("s_waitcnt vmcnt(2)" ::: "memory");
        } else {
            asm volatile("s_waitcnt vmcnt(0)" ::: "memory");
        }
        __builtin_amdgcn_s_barrier();
        __builtin_amdgcn_sched_barrier(0);
        compute(cur);
        __builtin_amdgcn_s_barrier();   // all reads of cur done before it is restaged
    }

    #pragma unroll
    for (int t = 0; t < RT; t++){
        int rb = m0 + wrbase + t*16 + ((lane >> 4) << 2);
        #pragma unroll
        for (int ct = 0; ct < CT; ct++){
            int col = wcbase + ct*16 + lane15;
            float bv = bias[col];
            #pragma unroll
            for (int r = 0; r < 4; r++){
                int row = rb + r;
                if (row < vc){
                    float val = acc[t][ct][r] + bv;
                    if (RELU) val = fmaxf(val, 0.f);
                    if (OUT_BF16)
                        reinterpret_cast<ushort_t*>(yout)[(size_t)row*BN + col] = f_to_bf16(val);
                    else
                        reinterpret_cast<float*>(yout)[(size_t)row*BN + col] = val;
                }
            }
        }
    }
}

extern "C" void kernel_launch(void* const* d_in, const int* in_sizes, int n_in,
                              void* d_out, int out_size, void* d_ws, size_t ws_size,
                              hipStream_t stream){
    const int*   src   = (const int*)d_in[0];
    const int*   dst   = (const int*)d_in[1];
    const int*   etype = (const int*)d_in[2];
    const float* norm  = (const float*)d_in[3];
    const float* emb   = (const float*)d_in[4];
    const float* V1    = (const float*)d_in[5];
    const float* comp1 = (const float*)d_in[6];
    const float* bias1 = (const float*)d_in[7];
    const float* V2    = (const float*)d_in[8];
    const float* comp2 = (const float*)d_in[9];
    const float* bias2 = (const float*)d_in[10];
    float* out = (float*)d_out;

    char* w = (char*)d_ws;
    auto alloc = [&](size_t bytes) -> char* {
        char* p = w; w += (bytes + 255) & ~(size_t)255; return p;
    };
    int*      offsets = (int*)alloc((NN + 1) * 4);
    int*      counts  = (int*)alloc(NN * 4);
    int*      cursor  = (int*)alloc(NN * 4);
    int*      tot     = (int*)alloc(SC_B * 4);
    int*      msrc    = (int*)alloc((size_t)EE * 4);
    int*      netn    = (int*)alloc((size_t)EE * 4);
    ushort_t* Wt1     = (ushort_t*)alloc((size_t)HH * KK * 2);
    ushort_t* Wt2     = (ushort_t*)alloc((size_t)OUTD * KK * 2);
    ushort_t* xb      = (ushort_t*)alloc((size_t)NN * HH * 2);
    ushort_t* h       = (ushort_t*)alloc((size_t)NN * HH * 2);
    size_t used  = (size_t)(w - (char*)d_ws);
    size_t avail = ws_size > used ? ws_size - used : 0;
    int chunkN = (int)(avail / ((size_t)KK * 2));
    chunkN &= ~127;
    if (chunkN < 128) chunkN = 128;
    if (chunkN > NN) chunkN = NN;
    ushort_t* agg = (ushort_t*)w;

    // CSR build + payload sort + weight/emb conversion
    zero_i32<<<(NN + 255)/256, 256, 0, stream>>>(counts, NN);
    hist_kernel<<<(EE + 255)/256, 256, 0, stream>>>(dst, counts);
    scan_part<<<SC_B, 256, 0, stream>>>(counts, tot);
    scan_tot<<<1, 64, 0, stream>>>(tot);
    scan_final<<<SC_B, 256, 0, stream>>>(counts, tot, offsets, cursor);
    scatter_kernel<<<(EE + 255)/256, 256, 0, stream>>>(dst, src, etype, norm,
                                                       cursor, msrc, netn);
    convw_kernel<<<((HH + OUTD)*KK + 255)/256, 256, 0, stream>>>(V1, V2, Wt1, Wt2);
    conv_emb<<<(NN*HH/2 + 255)/256, 256, 0, stream>>>(emb, xb);

    // layer 1: xb (bf16) -> h (bf16, relu)
    for (int v0 = 0; v0 < NN; v0 += chunkN){
        int vc = (NN - v0 < chunkN) ? (NN - v0) : chunkN;
        agg_kernel<<<(vc + 3)/4, 256, 0, stream>>>(
            xb, msrc, netn, offsets, comp1, agg, v0, vc);
        gemm_kernel<HH, true, true><<<(vc + 127)/128, 512, 0, stream>>>(
            agg, Wt1, bias1, h + (size_t)v0 * HH, vc);
    }
    // layer 2: h (bf16) -> out (f32)
    for (int v0 = 0; v0 < NN; v0 += chunkN){
        int vc = (NN - v0 < chunkN) ? (NN - v0) : chunkN;
        agg_kernel<<<(vc + 3)/4, 256, 0, stream>>>(
            h, msrc, netn, offsets, comp2, agg, v0, vc);
        gemm_kernel<OUTD, false, false><<<(vc + 127)/128, 512, 0, stream>>>(
            agg, Wt2, bias2, out + (size_t)v0 * OUTD, vc);
    }
}